// Round 13
// baseline (296.492 us; speedup 1.0000x reference)
//
#include <hip/hip_runtime.h>
#include <hip/hip_bf16.h>
#include <hip/hip_fp16.h>

#define IN_DIM 128
#define HID    64
#define OUTF   16
#define NGRAPH 500

#define CE    2048   // edges per chunk (256 threads x EPT 8)
#define NRNG  16     // dst ranges (25KB hist -> 6 blocks/CU in count)
#define CAP   256    // max matched edges per (chunk,range) segment; mean 128, +11 sigma
#define NG    32     // chunk-groups for the counting-sort CSR build
#define RSZ   6272   // LDS histogram size >= ceil(N/NRNG)=6250 (25088 B)

typedef _Float16 f16x8 __attribute__((ext_vector_type(8)));
typedef float    f32x4v __attribute__((ext_vector_type(4)));

// ---- fp16 pack/unpack helpers (f32 math, fp16 storage for gather tables) ----
__device__ __forceinline__ uint2 f4_to_h4(float4 a) {
    __half2 lo = __floats2half2_rn(a.x, a.y);
    __half2 hi = __floats2half2_rn(a.z, a.w);
    uint2 r;
    r.x = *(unsigned*)&lo;
    r.y = *(unsigned*)&hi;
    return r;
}
__device__ __forceinline__ float4 h4_to_f4(uint2 q) {
    __half2 a = *(__half2*)&q.x, b = *(__half2*)&q.y;
    float2 fa = __half22float2(a), fb = __half22float2(b);
    return make_float4(fa.x, fa.y, fb.x, fb.y);
}
__device__ __forceinline__ void h8_to_f8(uint4 p, float4& f0, float4& f1) {
    __half2 a = *(__half2*)&p.x, b = *(__half2*)&p.y;
    __half2 c = *(__half2*)&p.z, d = *(__half2*)&p.w;
    float2 fa = __half22float2(a), fb = __half22float2(b);
    float2 fc = __half22float2(c), fd = __half22float2(d);
    f0 = make_float4(fa.x, fa.y, fb.x, fb.y);
    f1 = make_float4(fc.x, fc.y, fd.x, fd.y);
}

// ---------------- MFMA GEMM: [N x K] @ [K x F] -> fp16 table ----------------
// Block = 64 rows, 4 waves; wave w owns rows w*16..w*16+15, all F/16 col-tiles.
// Frag layout (mfma_f32_16x16x32_f16): lane l holds operand row/col (l&15),
// k = (l>>4)*8 + 0..7; D: row=(l>>4)*4+reg, col=l&15 (guide §3, m89-verified).
template<int K, int F, bool INF16>
__global__ __launch_bounds__(256, 4) void mfma_gemm_kernel(const void* __restrict__ Xv,
                                                           const float* __restrict__ W,
                                                           __half* __restrict__ Hh, int N) {
    constexpr int Kp = K + 8;                 // f16 pad: keeps 16B row align, spreads banks
    constexpr int CT = F / 16;                // col tiles (4 or 1)
    __shared__ _Float16 sA[64 * Kp];
    __shared__ _Float16 sBt[F * Kp];
    const int tid = threadIdx.x;
    const int row0 = blockIdx.x * 64;

    // ---- stage X -> sA (f16) ----
    if (INF16) {
        const uint4* X8 = (const uint4*)Xv;   // 8 f16 per uint4
        constexpr int Q = K / 8;
        for (int i = tid; i < 64 * Q; i += 256) {
            int r = i / Q, q = i - r * Q;
            int gr = row0 + r;
            uint4 v = make_uint4(0u, 0u, 0u, 0u);
            if (gr < N) v = X8[(size_t)gr * Q + q];
            *(uint4*)&sA[r * Kp + q * 8] = v;
        }
    } else {
        const float4* X4 = (const float4*)Xv;
        constexpr int Q = K / 4;
        for (int i = tid; i < 64 * Q; i += 256) {
            int r = i / Q, q = i - r * Q;
            int gr = row0 + r;
            float4 v = {0.f, 0.f, 0.f, 0.f};
            if (gr < N) v = X4[(size_t)gr * Q + q];
            *(uint2*)&sA[r * Kp + q * 4] = f4_to_h4(v);
        }
    }
    // ---- stage W transposed -> sBt[col][k] (f16) ----
    {
        const float4* W4 = (const float4*)W;
        for (int i = tid; i < K * (F / 4); i += 256) {
            int k = i / (F / 4), c4 = i - k * (F / 4);
            float4 v = W4[i];
            sBt[(c4 * 4 + 0) * Kp + k] = (_Float16)v.x;
            sBt[(c4 * 4 + 1) * Kp + k] = (_Float16)v.y;
            sBt[(c4 * 4 + 2) * Kp + k] = (_Float16)v.z;
            sBt[(c4 * 4 + 3) * Kp + k] = (_Float16)v.w;
        }
    }
    __syncthreads();

    const int w = tid >> 6;          // wave id = row-tile
    const int l = tid & 63;
    const int m16 = l & 15;          // operand row (A) / col (B)
    const int kg = l >> 4;           // k-group -> k offset kg*8

    f32x4v acc[CT];
#pragma unroll
    for (int t = 0; t < CT; ++t) acc[t] = (f32x4v){0.f, 0.f, 0.f, 0.f};

    const _Float16* pa = &sA[(w * 16 + m16) * Kp + kg * 8];
#pragma unroll
    for (int k0 = 0; k0 < K; k0 += 32) {
        f16x8 af = *(const f16x8*)(pa + k0);
#pragma unroll
        for (int t = 0; t < CT; ++t) {
            f16x8 bf = *(const f16x8*)&sBt[(t * 16 + m16) * Kp + k0 + kg * 8];
            acc[t] = __builtin_amdgcn_mfma_f32_16x16x32_f16(af, bf, acc[t], 0, 0, 0);
        }
    }
    __syncthreads();
    // ---- repack D through LDS (reuse sA) for coalesced fp16 row stores ----
    _Float16* sOut = sA;
#pragma unroll
    for (int t = 0; t < CT; ++t) {
#pragma unroll
        for (int r = 0; r < 4; ++r) {
            int m = w * 16 + kg * 4 + r;       // D row
            int n = t * 16 + m16;              // D col
            sOut[m * F + n] = (_Float16)acc[t][r];
        }
    }
    __syncthreads();
    constexpr int U4 = (F * 2) / 16;           // uint4 per output row
    uint4* Ho = (uint4*)Hh;
    for (int i = tid; i < 64 * U4; i += 256) {
        int r = i / U4, q = i - r * U4;
        int gr = row0 + r;
        if (gr < N) Ho[(size_t)gr * U4 + q] = *(uint4*)&sOut[r * F + q * 8];
    }
}

// ---------------- part: single-scan range partitioning (no global atomics) ----
// Block 0 also zeroes the scan lookback state (consumed 2 dispatches later).
__global__ __launch_bounds__(256) void part_kernel(const int* __restrict__ src,
                                                   const int* __restrict__ dst,
                                                   uint2* __restrict__ seg,
                                                   int* __restrict__ segcnt,
                                                   unsigned* __restrict__ bstate,
                                                   int E, int rangeSize) {
    __shared__ uint2 sSeg[NRNG][CAP];   // 32 KB
    __shared__ int sCnt[NRNG];
    const int tid = threadIdx.x;
    if (blockIdx.x == 0 && tid < 128) bstate[tid] = 0u;
    if (tid < NRNG) sCnt[tid] = 0;
    __syncthreads();
    const int base = blockIdx.x * CE + tid;
    int d[8], s[8];
#pragma unroll
    for (int k = 0; k < 8; ++k) {
        int e = base + k * 256;
        d[k] = (e < E) ? dst[e] : -1;
        s[k] = (e < E) ? src[e] : 0;
    }
#pragma unroll
    for (int k = 0; k < 8; ++k) {
        if (d[k] >= 0) {
            int r = d[k] / rangeSize;
            int li = atomicAdd(&sCnt[r], 1);
            if (li < CAP) sSeg[r][li] = make_uint2((unsigned)s[k], (unsigned)d[k]);
        }
    }
    __syncthreads();
    for (int r = 0; r < NRNG; ++r) {
        int n = sCnt[r] < CAP ? sCnt[r] : CAP;
        uint2* out = seg + ((size_t)(blockIdx.x * NRNG + r)) * CAP;
        for (int i = tid; i < n; i += 256) out[i] = sSeg[r][i];
        if (tid == 0) segcnt[blockIdx.x * NRNG + r] = n;
    }
}

// ---------------- count: LDS histogram -> cnt matrix; stores per-edge rank ----
// The histogram atomicAdd's RETURN is the edge's rank within (g,r,d); packing
// it into seg.y bits [17..31] lets scatter run with no LDS and no atomics.
__global__ __launch_bounds__(256) void count_kernel(uint2* __restrict__ seg,
                                                    const int* __restrict__ segcnt,
                                                    int* __restrict__ cnt,
                                                    int N, int rangeSize, int nchunks) {
    __shared__ int hist[RSZ];
    const int r = blockIdx.x & (NRNG - 1);
    const int g = blockIdx.x / NRNG;
    const int cpg = (nchunks + NG - 1) / NG;
    const int c0 = g * cpg;
    const int c1 = (c0 + cpg < nchunks) ? c0 + cpg : nchunks;
    for (int i = threadIdx.x; i < rangeSize; i += 256) hist[i] = 0;
    __syncthreads();
    const int base = r * rangeSize;
    for (int c = c0; c < c1; ++c) {
        const int si = c * NRNG + r;
        const int n = segcnt[si];
        uint2* s = seg + (size_t)si * CAP;
        for (int i = threadIdx.x; i < n; i += 256) {
            uint2 v = s[i];
            int rank = atomicAdd(&hist[(int)v.y - base], 1);
            s[i] = make_uint2(v.x, ((unsigned)rank << 17) | v.y);
        }
    }
    __syncthreads();
    const int lim = (base + rangeSize <= N) ? rangeSize : (N - base);
    for (int i = threadIdx.x; i < lim; i += 256)
        cnt[(size_t)g * N + base + i] = hist[i];
}

// ---------------- scan1: group-scan + dis + block scan + DECOUPLED LOOKBACK ---
// Single-pass global prefix: block publishes {flag,total} packed in one word
// (flag bit31 = inclusive-prefix ready, bit30 = aggregate ready; E < 2^30).
// 98 blocks < 256 CUs => all co-resident; lookback waits only on lower ids.
// Replaces the old scan1+scan3 pair. Also zeroes pool sums/cnts + done flag.
__global__ __launch_bounds__(1024) void scan1_kernel(int* __restrict__ cnt,
                                                     int* __restrict__ rowptr,
                                                     unsigned* __restrict__ bstate,
                                                     float* __restrict__ dis,
                                                     float* __restrict__ pool0, int N) {
    if (blockIdx.x == 0) {
        for (int i = threadIdx.x; i < NGRAPH * OUTF + NGRAPH + 1; i += 1024) pool0[i] = 0.f;
    }
    __shared__ int s[1024];
    __shared__ int sExcl;
    int i = blockIdx.x * 1024 + threadIdx.x;
    int v = 0;
    if (i < N) {
        int run = 0;
#pragma unroll
        for (int g = 0; g < NG; ++g) {          // coalesced RMW column walk
            const size_t idx = (size_t)g * N + i;
            int c = cnt[idx];
            cnt[idx] = run;
            run += c;
        }
        v = run;
        dis[i] = rsqrtf(1.0f + (float)v);
    }
    s[threadIdx.x] = v;
    __syncthreads();
    for (int off = 1; off < 1024; off <<= 1) {
        int t = (threadIdx.x >= off) ? s[threadIdx.x - off] : 0;
        __syncthreads();
        s[threadIdx.x] += t;
        __syncthreads();
    }
    const int total = s[1023];
    if (threadIdx.x == 0) {
        if (blockIdx.x == 0) {
            atomicExch(&bstate[0], 0x80000000u | (unsigned)total);
            sExcl = 0;
        } else {
            atomicExch(&bstate[blockIdx.x], 0x40000000u | (unsigned)total);
            int excl = 0;
            int j = blockIdx.x - 1;
            while (j >= 0) {
                unsigned st = atomicAdd(&bstate[j], 0u);    // atomic read
                if (st & 0x80000000u) { excl += (int)(st & 0x3FFFFFFFu); break; }
                if (st & 0x40000000u) { excl += (int)(st & 0x3FFFFFFFu); --j; }
                // else: predecessor not published yet -> spin
            }
            atomicExch(&bstate[blockIdx.x], 0x80000000u | (unsigned)(excl + total));
            sExcl = excl;
        }
    }
    __syncthreads();
    if (i < N) rowptr[i] = s[threadIdx.x] - v + sExcl;      // final exclusive prefix
}

// ---------------- scatter: pure streaming (ranks precomputed by count) --------
__global__ __launch_bounds__(256) void scatter_kernel(const uint2* __restrict__ seg,
                                                      const int* __restrict__ segcnt,
                                                      const int* __restrict__ cntp,
                                                      const int* __restrict__ rowptr,
                                                      int* __restrict__ csr_src,
                                                      int N, int rangeSize, int nchunks) {
    const int r = blockIdx.x & (NRNG - 1);
    const int g = blockIdx.x / NRNG;
    const int cpg = (nchunks + NG - 1) / NG;
    const int c0 = g * cpg;
    const int c1 = (c0 + cpg < nchunks) ? c0 + cpg : nchunks;
    for (int c = c0; c < c1; ++c) {
        const int si = c * NRNG + r;
        const int n = segcnt[si];
        const uint2* s = seg + (size_t)si * CAP;
        for (int i = threadIdx.x; i < n; i += 256) {
            uint2 v = s[i];
            const int d = (int)(v.y & 0x1FFFFu);
            const int rank = (int)(v.y >> 17);
            csr_src[rowptr[d] + cntp[(size_t)g * N + d] + rank] = (int)v.x;
        }
    }
}

// ---------------- fused aggregate + self-loop + bias + relu, F=64, fp16 out ---
// 4 nodes/wave (16 lanes: 2 edge-groups x 8 chunk lanes), 2-deep pipeline.
__global__ __launch_bounds__(256) void agg64_kernel(const __half* __restrict__ Hh,
                                                    const int* __restrict__ rowptr,
                                                    const int* __restrict__ csr_src,
                                                    const float* __restrict__ dis,
                                                    const float4* __restrict__ b4,
                                                    uint4* __restrict__ outh, int N, int E) {
    const int tid = threadIdx.x;
    const int lane = tid & 63;
    const int node = blockIdx.x * 16 + (tid >> 6) * 4 + (lane >> 4);
    const int g2 = (lane >> 3) & 1;
    const int c = lane & 7;
    if (node >= N) return;
    const uint4* Hh4 = (const uint4*)Hh;
    float dd = dis[node];
    int i0 = rowptr[node];
    int i1 = (node + 1 < N) ? rowptr[node + 1] : E;
    float4 a0 = {0.f, 0.f, 0.f, 0.f}, a1 = {0.f, 0.f, 0.f, 0.f};
    int i = i0 + g2;
    int iB = i + 2;
    int sA = (i < i1) ? csr_src[i] : 0;
    int sB = (iB < i1) ? csr_src[iB] : 0;
    uint4 pA = make_uint4(0u, 0u, 0u, 0u);
    float wA = 0.f;
    if (i < i1) {
        pA = Hh4[(long long)sA * 8 + c];
        wA = dis[sA] * dd;
    }
    while (i < i1) {
        const int iC = i + 4;
        int sC = (iC < i1) ? csr_src[iC] : 0;
        uint4 pB = Hh4[(long long)sB * 8 + c];
        float wB = (iB < i1) ? dis[sB] * dd : 0.f;
        float4 v0, v1;
        h8_to_f8(pA, v0, v1);
        a0.x += v0.x * wA; a0.y += v0.y * wA; a0.z += v0.z * wA; a0.w += v0.w * wA;
        a1.x += v1.x * wA; a1.y += v1.y * wA; a1.z += v1.z * wA; a1.w += v1.w * wA;
        i = iB; iB = iC; sA = sB; sB = sC; pA = pB; wA = wB;
    }
    a0.x += __shfl_xor(a0.x, 8); a0.y += __shfl_xor(a0.y, 8);
    a0.z += __shfl_xor(a0.z, 8); a0.w += __shfl_xor(a0.w, 8);
    a1.x += __shfl_xor(a1.x, 8); a1.y += __shfl_xor(a1.y, 8);
    a1.z += __shfl_xor(a1.z, 8); a1.w += __shfl_xor(a1.w, 8);
    if (g2 == 0) {
        float sl = dd * dd;
        uint4 ps = Hh4[(long long)node * 8 + c];
        float4 h0, h1;
        h8_to_f8(ps, h0, h1);
        float4 bb0 = b4[2 * c], bb1 = b4[2 * c + 1];
        a0.x += h0.x * sl + bb0.x; a0.y += h0.y * sl + bb0.y;
        a0.z += h0.z * sl + bb0.z; a0.w += h0.w * sl + bb0.w;
        a1.x += h1.x * sl + bb1.x; a1.y += h1.y * sl + bb1.y;
        a1.z += h1.z * sl + bb1.z; a1.w += h1.w * sl + bb1.w;
        a0.x = fmaxf(a0.x, 0.f); a0.y = fmaxf(a0.y, 0.f);
        a0.z = fmaxf(a0.z, 0.f); a0.w = fmaxf(a0.w, 0.f);
        a1.x = fmaxf(a1.x, 0.f); a1.y = fmaxf(a1.y, 0.f);
        a1.z = fmaxf(a1.z, 0.f); a1.w = fmaxf(a1.w, 0.f);
        uint2 lo = f4_to_h4(a0), hi = f4_to_h4(a1);
        outh[(long long)node * 8 + c] = make_uint4(lo.x, lo.y, hi.x, hi.y);
    }
}

// ---------------- F=16: 8 nodes/wave, 2-deep pipeline, f32 out (pool input) ---
__global__ __launch_bounds__(256) void agg16_kernel(const __half* __restrict__ Hh,
                                                    const int* __restrict__ rowptr,
                                                    const int* __restrict__ csr_src,
                                                    const float* __restrict__ dis,
                                                    const float4* __restrict__ b4,
                                                    float4* __restrict__ out4, int N, int E) {
    const int tid = threadIdx.x;
    const int lane = tid & 63;
    const int node = blockIdx.x * 32 + (tid >> 6) * 8 + (lane >> 3);
    const int g2 = (lane >> 2) & 1;
    const int c = lane & 3;
    if (node >= N) return;
    const uint2* Hh2 = (const uint2*)Hh;
    float dd = dis[node];
    int i0 = rowptr[node];
    int i1 = (node + 1 < N) ? rowptr[node + 1] : E;
    float4 acc = {0.f, 0.f, 0.f, 0.f};
    int i = i0 + g2;
    int iB = i + 2;
    int sA = (i < i1) ? csr_src[i] : 0;
    int sB = (iB < i1) ? csr_src[iB] : 0;
    uint2 pA = make_uint2(0u, 0u);
    float wA = 0.f;
    if (i < i1) {
        pA = Hh2[(long long)sA * 4 + c];
        wA = dis[sA] * dd;
    }
    while (i < i1) {
        const int iC = i + 4;
        int sC = (iC < i1) ? csr_src[iC] : 0;
        uint2 pB = Hh2[(long long)sB * 4 + c];
        float wB = (iB < i1) ? dis[sB] * dd : 0.f;
        float4 v = h4_to_f4(pA);
        acc.x += v.x * wA; acc.y += v.y * wA;
        acc.z += v.z * wA; acc.w += v.w * wA;
        i = iB; iB = iC; sA = sB; sB = sC; pA = pB; wA = wB;
    }
    acc.x += __shfl_xor(acc.x, 4);
    acc.y += __shfl_xor(acc.y, 4);
    acc.z += __shfl_xor(acc.z, 4);
    acc.w += __shfl_xor(acc.w, 4);
    if (g2 == 0) {
        float4 h = h4_to_f4(Hh2[(long long)node * 4 + c]);
        float sl = dd * dd;
        float4 bb = b4[c];
        acc.x += h.x * sl + bb.x; acc.y += h.y * sl + bb.y;
        acc.z += h.z * sl + bb.z; acc.w += h.w * sl + bb.w;
        out4[(long long)node * 4 + c] = acc;
    }
}

// ---------------- pooling + fused divide (last-block-done pattern) ------------
__global__ __launch_bounds__(256) void pool_kernel(const float4* __restrict__ H4,
                                                   const int* __restrict__ batch,
                                                   float* __restrict__ sums,
                                                   float* __restrict__ cnts,
                                                   unsigned* __restrict__ done,
                                                   float* __restrict__ out, int N) {
    __shared__ float sBin[16][16];
    __shared__ float sCnt[16];
    __shared__ int sLast;
    const int t = threadIdx.x;
    sBin[t >> 4][t & 15] = 0.f;
    if (t < 16) sCnt[t] = 0.f;
    __syncthreads();
    const int n0 = blockIdx.x * 256;
    const int g0 = batch[n0];
    const int nl = t >> 2;
    const int f4 = t & 3;
    float4 acc = {0.f, 0.f, 0.f, 0.f};
    float cnt = 0.f;
    int curli = -1;
    for (int j = 0; j < 4; ++j) {
        int node = n0 + nl * 4 + j;
        if (node >= N) break;
        int li = batch[node] - g0;
        if (li != curli) {
            if (curli >= 0) {
                if (curli < 16) {
                    float* bp = &sBin[curli][f4 * 4];
                    atomicAdd(bp + 0, acc.x); atomicAdd(bp + 1, acc.y);
                    atomicAdd(bp + 2, acc.z); atomicAdd(bp + 3, acc.w);
                    if (f4 == 0) atomicAdd(&sCnt[curli], cnt);
                } else {
                    float* gp = &sums[(g0 + curli) * OUTF + f4 * 4];
                    atomicAdd(gp + 0, acc.x); atomicAdd(gp + 1, acc.y);
                    atomicAdd(gp + 2, acc.z); atomicAdd(gp + 3, acc.w);
                    if (f4 == 0) atomicAdd(&cnts[g0 + curli], cnt);
                }
            }
            acc.x = acc.y = acc.z = acc.w = 0.f; cnt = 0.f; curli = li;
        }
        float4 v = H4[(long long)node * 4 + f4];
        acc.x += v.x; acc.y += v.y; acc.z += v.z; acc.w += v.w;
        cnt += 1.f;
    }
    if (curli >= 0) {
        if (curli < 16) {
            float* bp = &sBin[curli][f4 * 4];
            atomicAdd(bp + 0, acc.x); atomicAdd(bp + 1, acc.y);
            atomicAdd(bp + 2, acc.z); atomicAdd(bp + 3, acc.w);
            if (f4 == 0) atomicAdd(&sCnt[curli], cnt);
        } else {
            float* gp = &sums[(g0 + curli) * OUTF + f4 * 4];
            atomicAdd(gp + 0, acc.x); atomicAdd(gp + 1, acc.y);
            atomicAdd(gp + 2, acc.z); atomicAdd(gp + 3, acc.w);
            if (f4 == 0) atomicAdd(&cnts[g0 + curli], cnt);
        }
    }
    __syncthreads();
    int bg = t >> 4, bf = t & 15;
    int g = g0 + bg;
    if (g < NGRAPH) {
        float v = sBin[bg][bf];
        if (v != 0.f) atomicAdd(&sums[g * OUTF + bf], v);
        if (bf == 0) {
            float c = sCnt[bg];
            if (c != 0.f) atomicAdd(&cnts[g], c);
        }
    }
    // ---- last block performs the divide (all prior atomics device-visible) ----
    __threadfence();
    if (t == 0) sLast = (atomicAdd(done, 1u) == gridDim.x - 1) ? 1 : 0;
    __syncthreads();
    if (sLast) {
        for (int i = t; i < NGRAPH * OUTF; i += 256)
            out[i] = sums[i] / fmaxf(cnts[i >> 4], 1.0f);
    }
}

extern "C" void kernel_launch(void* const* d_in, const int* in_sizes, int n_in,
                              void* d_out, int out_size, void* d_ws, size_t ws_size,
                              hipStream_t stream) {
    const float* x     = (const float*)d_in[0];
    const int*   ei    = (const int*)d_in[1];
    const int*   batch = (const int*)d_in[2];
    const float* W1 = (const float*)d_in[3];
    const float* b1 = (const float*)d_in[4];
    const float* W2 = (const float*)d_in[5];
    const float* b2 = (const float*)d_in[6];
    const float* W3 = (const float*)d_in[7];
    const float* b3 = (const float*)d_in[8];
    float* out = (float*)d_out;

    const int N = in_sizes[2];          // 100000
    const int E = in_sizes[1] / 2;      // 1200000
    const int* src = ei;
    const int* dst = ei + E;

    const int nchunks = (E + CE - 1) / CE;        // 586
    const int NGB = NG * NRNG;                    // 512 counting-sort blocks

    // workspace layout (4-byte units)
    float*    ws      = (float*)d_ws;
    float*    dis     = ws;                          // N floats
    float*    bufA    = dis + N;                     // 25.6 MB: cntmat -> T1/T2/T3 fp16 tables
    float*    bufB    = bufA + (size_t)N * HID;      // 25.6 MB: seg -> A1/A2 fp16 -> f32 pool in
    float*    sums    = bufB + (size_t)N * HID;      // 500*16
    float*    cnts    = sums + NGRAPH * OUTF;        // 500
    unsigned* done    = (unsigned*)(cnts + NGRAPH);  // 1 (zeroed with pool0 region)
    int*      rowptr  = (int*)(done + 1);            // N ints
    int*      csr_src = rowptr + N;                  // E ints
    int*      segcnt  = csr_src + E;                 // nseg ints
    unsigned* bstate  = (unsigned*)(segcnt + nchunks * NRNG);  // 128 words (lookback)
    uint2*    seg     = (uint2*)bufB;                // nseg*CAP uint2 = 19.2 MB < 25.6 MB
    int*      cntmat  = (int*)bufA;                  // NG*N ints = 12.8 MB < 25.6 MB
    __half*   HhA     = (__half*)bufA;               // fp16 tables (after cntmat dead)
    __half*   HhB     = (__half*)bufB;               // fp16 agg out (after seg dead)

    const int B = 256;
    const int nb = (N + 1023) / 1024;               // 98 blocks (< 256 CUs)
    const int rangeSize = (N + NRNG - 1) / NRNG;

    // ---- CSR build: atomic-free counting sort; single-pass lookback scan
    part_kernel<<<nchunks, B, 0, stream>>>(src, dst, seg, segcnt, bstate, E, rangeSize);
    count_kernel<<<NGB, B, 0, stream>>>(seg, segcnt, cntmat, N, rangeSize, nchunks);
    scan1_kernel<<<nb, 1024, 0, stream>>>(cntmat, rowptr, bstate, dis, sums, N);
    scatter_kernel<<<NGB, B, 0, stream>>>(seg, segcnt, cntmat, rowptr, csr_src, N, rangeSize, nchunks);

    const int gb = (N + 63) / 64;

    // ---- layer 1: x @ W1 -> T1 (bufA, fp16) ----
    mfma_gemm_kernel<IN_DIM, HID, false><<<gb, B, 0, stream>>>(x, W1, HhA, N);
    agg64_kernel<<<(N + 15) / 16, B, 0, stream>>>(HhA, rowptr, csr_src,
                                                  dis, (const float4*)b1, (uint4*)HhB, N, E);

    // ---- layer 2: A1 @ W2 -> T2 (bufA, fp16) ----
    mfma_gemm_kernel<HID, HID, true><<<gb, B, 0, stream>>>(HhB, W2, HhA, N);
    agg64_kernel<<<(N + 15) / 16, B, 0, stream>>>(HhA, rowptr, csr_src,
                                                  dis, (const float4*)b2, (uint4*)HhB, N, E);

    // ---- layer 3: A2 @ W3 -> T3 (bufA, fp16) ----
    mfma_gemm_kernel<HID, OUTF, true><<<gb, B, 0, stream>>>(HhB, W3, HhA, N);
    //      agg16(T3) -> pool input (bufB, f32; seg dead)
    agg16_kernel<<<(N + 31) / 32, B, 0, stream>>>(HhA, rowptr, csr_src,
                                                  dis, (const float4*)b3, (float4*)bufB, N, E);

    // ---- global mean pool + fused divide ----
    pool_kernel<<<(N + 255) / 256, B, 0, stream>>>((const float4*)bufB, batch, sums, cnts,
                                                   done, out, N);
}

// Round 14
// 266.733 us; speedup vs baseline: 1.1116x; 1.1116x over previous
//
#include <hip/hip_runtime.h>
#include <hip/hip_bf16.h>
#include <hip/hip_fp16.h>

#define IN_DIM 128
#define HID    64
#define OUTF   16
#define NGRAPH 500

#define CE    2048   // edges per chunk (256 threads x EPT 8)
#define NRNG  16     // dst ranges (25KB hist -> 6 blocks/CU in count)
#define CAP   256    // max matched edges per (chunk,range) segment; mean 128, +11 sigma
#define NG    32     // chunk-groups for the counting-sort CSR build
#define RSZ   6272   // LDS histogram size >= ceil(N/NRNG)=6250 (25088 B)

typedef _Float16 f16x8 __attribute__((ext_vector_type(8)));
typedef float    f32x4v __attribute__((ext_vector_type(4)));

// ---- fp16 pack/unpack helpers (f32 math, fp16 storage for gather tables) ----
__device__ __forceinline__ uint2 f4_to_h4(float4 a) {
    __half2 lo = __floats2half2_rn(a.x, a.y);
    __half2 hi = __floats2half2_rn(a.z, a.w);
    uint2 r;
    r.x = *(unsigned*)&lo;
    r.y = *(unsigned*)&hi;
    return r;
}
__device__ __forceinline__ float4 h4_to_f4(uint2 q) {
    __half2 a = *(__half2*)&q.x, b = *(__half2*)&q.y;
    float2 fa = __half22float2(a), fb = __half22float2(b);
    return make_float4(fa.x, fa.y, fb.x, fb.y);
}
__device__ __forceinline__ void h8_to_f8(uint4 p, float4& f0, float4& f1) {
    __half2 a = *(__half2*)&p.x, b = *(__half2*)&p.y;
    __half2 c = *(__half2*)&p.z, d = *(__half2*)&p.w;
    float2 fa = __half22float2(a), fb = __half22float2(b);
    float2 fc = __half22float2(c), fd = __half22float2(d);
    f0 = make_float4(fa.x, fa.y, fb.x, fb.y);
    f1 = make_float4(fc.x, fc.y, fd.x, fd.y);
}

// ---------------- MFMA GEMM: [N x K] @ [K x F] -> fp16 table ----------------
// Block = 64 rows, 4 waves; wave w owns rows w*16..w*16+15, all F/16 col-tiles.
// Frag layout (mfma_f32_16x16x32_f16): lane l holds operand row/col (l&15),
// k = (l>>4)*8 + 0..7; D: row=(l>>4)*4+reg, col=l&15 (guide §3, m89-verified).
template<int K, int F, bool INF16>
__global__ __launch_bounds__(256, 4) void mfma_gemm_kernel(const void* __restrict__ Xv,
                                                           const float* __restrict__ W,
                                                           __half* __restrict__ Hh, int N) {
    constexpr int Kp = K + 8;                 // f16 pad: keeps 16B row align, spreads banks
    constexpr int CT = F / 16;                // col tiles (4 or 1)
    __shared__ _Float16 sA[64 * Kp];
    __shared__ _Float16 sBt[F * Kp];
    const int tid = threadIdx.x;
    const int row0 = blockIdx.x * 64;

    // ---- stage X -> sA (f16) ----
    if (INF16) {
        const uint4* X8 = (const uint4*)Xv;   // 8 f16 per uint4
        constexpr int Q = K / 8;
        for (int i = tid; i < 64 * Q; i += 256) {
            int r = i / Q, q = i - r * Q;
            int gr = row0 + r;
            uint4 v = make_uint4(0u, 0u, 0u, 0u);
            if (gr < N) v = X8[(size_t)gr * Q + q];
            *(uint4*)&sA[r * Kp + q * 8] = v;
        }
    } else {
        const float4* X4 = (const float4*)Xv;
        constexpr int Q = K / 4;
        for (int i = tid; i < 64 * Q; i += 256) {
            int r = i / Q, q = i - r * Q;
            int gr = row0 + r;
            float4 v = {0.f, 0.f, 0.f, 0.f};
            if (gr < N) v = X4[(size_t)gr * Q + q];
            *(uint2*)&sA[r * Kp + q * 4] = f4_to_h4(v);
        }
    }
    // ---- stage W transposed -> sBt[col][k] (f16) ----
    {
        const float4* W4 = (const float4*)W;
        for (int i = tid; i < K * (F / 4); i += 256) {
            int k = i / (F / 4), c4 = i - k * (F / 4);
            float4 v = W4[i];
            sBt[(c4 * 4 + 0) * Kp + k] = (_Float16)v.x;
            sBt[(c4 * 4 + 1) * Kp + k] = (_Float16)v.y;
            sBt[(c4 * 4 + 2) * Kp + k] = (_Float16)v.z;
            sBt[(c4 * 4 + 3) * Kp + k] = (_Float16)v.w;
        }
    }
    __syncthreads();

    const int w = tid >> 6;          // wave id = row-tile
    const int l = tid & 63;
    const int m16 = l & 15;          // operand row (A) / col (B)
    const int kg = l >> 4;           // k-group -> k offset kg*8

    f32x4v acc[CT];
#pragma unroll
    for (int t = 0; t < CT; ++t) acc[t] = (f32x4v){0.f, 0.f, 0.f, 0.f};

    const _Float16* pa = &sA[(w * 16 + m16) * Kp + kg * 8];
#pragma unroll
    for (int k0 = 0; k0 < K; k0 += 32) {
        f16x8 af = *(const f16x8*)(pa + k0);
#pragma unroll
        for (int t = 0; t < CT; ++t) {
            f16x8 bf = *(const f16x8*)&sBt[(t * 16 + m16) * Kp + k0 + kg * 8];
            acc[t] = __builtin_amdgcn_mfma_f32_16x16x32_f16(af, bf, acc[t], 0, 0, 0);
        }
    }
    __syncthreads();
    // ---- repack D through LDS (reuse sA) for coalesced fp16 row stores ----
    _Float16* sOut = sA;
#pragma unroll
    for (int t = 0; t < CT; ++t) {
#pragma unroll
        for (int r = 0; r < 4; ++r) {
            int m = w * 16 + kg * 4 + r;       // D row
            int n = t * 16 + m16;              // D col
            sOut[m * F + n] = (_Float16)acc[t][r];
        }
    }
    __syncthreads();
    constexpr int U4 = (F * 2) / 16;           // uint4 per output row
    uint4* Ho = (uint4*)Hh;
    for (int i = tid; i < 64 * U4; i += 256) {
        int r = i / U4, q = i - r * U4;
        int gr = row0 + r;
        if (gr < N) Ho[(size_t)gr * U4 + q] = *(uint4*)&sOut[r * F + q * 8];
    }
}

// ---------------- part: single-scan range partitioning (no global atomics) ----
__global__ __launch_bounds__(256) void part_kernel(const int* __restrict__ src,
                                                   const int* __restrict__ dst,
                                                   uint2* __restrict__ seg,
                                                   int* __restrict__ segcnt,
                                                   int E, int rangeSize) {
    __shared__ uint2 sSeg[NRNG][CAP];   // 32 KB
    __shared__ int sCnt[NRNG];
    const int tid = threadIdx.x;
    if (tid < NRNG) sCnt[tid] = 0;
    __syncthreads();
    const int base = blockIdx.x * CE + tid;
    int d[8], s[8];
#pragma unroll
    for (int k = 0; k < 8; ++k) {
        int e = base + k * 256;
        d[k] = (e < E) ? dst[e] : -1;
        s[k] = (e < E) ? src[e] : 0;
    }
#pragma unroll
    for (int k = 0; k < 8; ++k) {
        if (d[k] >= 0) {
            int r = d[k] / rangeSize;
            int li = atomicAdd(&sCnt[r], 1);
            if (li < CAP) sSeg[r][li] = make_uint2((unsigned)s[k], (unsigned)d[k]);
        }
    }
    __syncthreads();
    for (int r = 0; r < NRNG; ++r) {
        int n = sCnt[r] < CAP ? sCnt[r] : CAP;
        uint2* out = seg + ((size_t)(blockIdx.x * NRNG + r)) * CAP;
        for (int i = tid; i < n; i += 256) out[i] = sSeg[r][i];
        if (tid == 0) segcnt[blockIdx.x * NRNG + r] = n;
    }
}

// ---------------- count: LDS histogram -> cnt matrix; stores per-edge rank ----
// The histogram atomicAdd's RETURN is the edge's rank within (g,r,d); packing
// it into seg.y bits [17..31] lets scatter run with no LDS and no atomics.
__global__ __launch_bounds__(256) void count_kernel(uint2* __restrict__ seg,
                                                    const int* __restrict__ segcnt,
                                                    int* __restrict__ cnt,
                                                    int N, int rangeSize, int nchunks) {
    __shared__ int hist[RSZ];
    const int r = blockIdx.x & (NRNG - 1);
    const int g = blockIdx.x / NRNG;
    const int cpg = (nchunks + NG - 1) / NG;
    const int c0 = g * cpg;
    const int c1 = (c0 + cpg < nchunks) ? c0 + cpg : nchunks;
    for (int i = threadIdx.x; i < rangeSize; i += 256) hist[i] = 0;
    __syncthreads();
    const int base = r * rangeSize;
    for (int c = c0; c < c1; ++c) {
        const int si = c * NRNG + r;
        const int n = segcnt[si];
        uint2* s = seg + (size_t)si * CAP;
        for (int i = threadIdx.x; i < n; i += 256) {
            uint2 v = s[i];
            int rank = atomicAdd(&hist[(int)v.y - base], 1);
            s[i] = make_uint2(v.x, ((unsigned)rank << 17) | v.y);
        }
    }
    __syncthreads();
    const int lim = (base + rangeSize <= N) ? rangeSize : (N - base);
    for (int i = threadIdx.x; i < lim; i += 256)
        cnt[(size_t)g * N + base + i] = hist[i];
}

// ---------------- scan1 (merged nodescan): group-scan + dis + block scan ------
__global__ __launch_bounds__(1024) void scan1_kernel(int* __restrict__ cnt,
                                                     int* __restrict__ rowptr,
                                                     int* __restrict__ aux,
                                                     float* __restrict__ dis,
                                                     float* __restrict__ pool0, int N) {
    if (blockIdx.x == 0) {
        for (int i = threadIdx.x; i < NGRAPH * OUTF + NGRAPH; i += 1024) pool0[i] = 0.f;
    }
    __shared__ int s[1024];
    int i = blockIdx.x * 1024 + threadIdx.x;
    int v = 0;
    if (i < N) {
        int run = 0;
#pragma unroll
        for (int g = 0; g < NG; ++g) {
            const size_t idx = (size_t)g * N + i;
            int c = cnt[idx];
            cnt[idx] = run;
            run += c;
        }
        v = run;
        dis[i] = rsqrtf(1.0f + (float)v);
    }
    s[threadIdx.x] = v;
    __syncthreads();
    for (int off = 1; off < 1024; off <<= 1) {
        int t = (threadIdx.x >= off) ? s[threadIdx.x - off] : 0;
        __syncthreads();
        s[threadIdx.x] += t;
        __syncthreads();
    }
    if (i < N) rowptr[i] = s[threadIdx.x] - v;
    if (threadIdx.x == 1023) aux[blockIdx.x] = s[1023];
}

// ---------------- scan3: merged aux-scan + apply ----------------
__global__ __launch_bounds__(1024) void scan3_kernel(int* __restrict__ rowptr,
                                                     const int* __restrict__ aux,
                                                     int N, int nb) {
    __shared__ int s[128];
    const int t = threadIdx.x;
    if (t < 128) s[t] = (t < nb) ? aux[t] : 0;
    __syncthreads();
    for (int off = 1; off < 128; off <<= 1) {
        int v = (t >= off && t < 128) ? s[t - off] : 0;
        __syncthreads();
        if (t < 128) s[t] += v;
        __syncthreads();
    }
    int add = (blockIdx.x == 0) ? 0 : s[blockIdx.x - 1];
    int i = blockIdx.x * 1024 + t;
    if (i < N) rowptr[i] += add;
}

// ---------------- scatter: pure streaming (ranks precomputed by count) --------
__global__ __launch_bounds__(256) void scatter_kernel(const uint2* __restrict__ seg,
                                                      const int* __restrict__ segcnt,
                                                      const int* __restrict__ cntp,
                                                      const int* __restrict__ rowptr,
                                                      int* __restrict__ csr_src,
                                                      int N, int rangeSize, int nchunks) {
    const int r = blockIdx.x & (NRNG - 1);
    const int g = blockIdx.x / NRNG;
    const int cpg = (nchunks + NG - 1) / NG;
    const int c0 = g * cpg;
    const int c1 = (c0 + cpg < nchunks) ? c0 + cpg : nchunks;
    for (int c = c0; c < c1; ++c) {
        const int si = c * NRNG + r;
        const int n = segcnt[si];
        const uint2* s = seg + (size_t)si * CAP;
        for (int i = threadIdx.x; i < n; i += 256) {
            uint2 v = s[i];
            const int d = (int)(v.y & 0x1FFFFu);
            const int rank = (int)(v.y >> 17);
            csr_src[rowptr[d] + cntp[(size_t)g * N + d] + rank] = (int)v.x;
        }
    }
}

// ---------------- fused aggregate + self-loop + bias + relu, F=64, fp16 out ---
// 4 nodes/wave (16 lanes: 2 edge-groups x 8 chunk lanes), 2-deep pipeline.
__global__ __launch_bounds__(256) void agg64_kernel(const __half* __restrict__ Hh,
                                                    const int* __restrict__ rowptr,
                                                    const int* __restrict__ csr_src,
                                                    const float* __restrict__ dis,
                                                    const float4* __restrict__ b4,
                                                    uint4* __restrict__ outh, int N, int E) {
    const int tid = threadIdx.x;
    const int lane = tid & 63;
    const int node = blockIdx.x * 16 + (tid >> 6) * 4 + (lane >> 4);
    const int g2 = (lane >> 3) & 1;
    const int c = lane & 7;
    if (node >= N) return;
    const uint4* Hh4 = (const uint4*)Hh;
    float dd = dis[node];
    int i0 = rowptr[node];
    int i1 = (node + 1 < N) ? rowptr[node + 1] : E;
    float4 a0 = {0.f, 0.f, 0.f, 0.f}, a1 = {0.f, 0.f, 0.f, 0.f};
    int i = i0 + g2;
    int iB = i + 2;
    int sA = (i < i1) ? csr_src[i] : 0;
    int sB = (iB < i1) ? csr_src[iB] : 0;
    uint4 pA = make_uint4(0u, 0u, 0u, 0u);
    float wA = 0.f;
    if (i < i1) {
        pA = Hh4[(long long)sA * 8 + c];
        wA = dis[sA] * dd;
    }
    while (i < i1) {
        const int iC = i + 4;
        int sC = (iC < i1) ? csr_src[iC] : 0;
        uint4 pB = Hh4[(long long)sB * 8 + c];
        float wB = (iB < i1) ? dis[sB] * dd : 0.f;
        float4 v0, v1;
        h8_to_f8(pA, v0, v1);
        a0.x += v0.x * wA; a0.y += v0.y * wA; a0.z += v0.z * wA; a0.w += v0.w * wA;
        a1.x += v1.x * wA; a1.y += v1.y * wA; a1.z += v1.z * wA; a1.w += v1.w * wA;
        i = iB; iB = iC; sA = sB; sB = sC; pA = pB; wA = wB;
    }
    a0.x += __shfl_xor(a0.x, 8); a0.y += __shfl_xor(a0.y, 8);
    a0.z += __shfl_xor(a0.z, 8); a0.w += __shfl_xor(a0.w, 8);
    a1.x += __shfl_xor(a1.x, 8); a1.y += __shfl_xor(a1.y, 8);
    a1.z += __shfl_xor(a1.z, 8); a1.w += __shfl_xor(a1.w, 8);
    if (g2 == 0) {
        float sl = dd * dd;
        uint4 ps = Hh4[(long long)node * 8 + c];
        float4 h0, h1;
        h8_to_f8(ps, h0, h1);
        float4 bb0 = b4[2 * c], bb1 = b4[2 * c + 1];
        a0.x += h0.x * sl + bb0.x; a0.y += h0.y * sl + bb0.y;
        a0.z += h0.z * sl + bb0.z; a0.w += h0.w * sl + bb0.w;
        a1.x += h1.x * sl + bb1.x; a1.y += h1.y * sl + bb1.y;
        a1.z += h1.z * sl + bb1.z; a1.w += h1.w * sl + bb1.w;
        a0.x = fmaxf(a0.x, 0.f); a0.y = fmaxf(a0.y, 0.f);
        a0.z = fmaxf(a0.z, 0.f); a0.w = fmaxf(a0.w, 0.f);
        a1.x = fmaxf(a1.x, 0.f); a1.y = fmaxf(a1.y, 0.f);
        a1.z = fmaxf(a1.z, 0.f); a1.w = fmaxf(a1.w, 0.f);
        uint2 lo = f4_to_h4(a0), hi = f4_to_h4(a1);
        outh[(long long)node * 8 + c] = make_uint4(lo.x, lo.y, hi.x, hi.y);
    }
}

// ---------------- F=16: 8 nodes/wave, 2-deep pipeline, f32 out (pool input) ---
__global__ __launch_bounds__(256) void agg16_kernel(const __half* __restrict__ Hh,
                                                    const int* __restrict__ rowptr,
                                                    const int* __restrict__ csr_src,
                                                    const float* __restrict__ dis,
                                                    const float4* __restrict__ b4,
                                                    float4* __restrict__ out4, int N, int E) {
    const int tid = threadIdx.x;
    const int lane = tid & 63;
    const int node = blockIdx.x * 32 + (tid >> 6) * 8 + (lane >> 3);
    const int g2 = (lane >> 2) & 1;
    const int c = lane & 3;
    if (node >= N) return;
    const uint2* Hh2 = (const uint2*)Hh;
    float dd = dis[node];
    int i0 = rowptr[node];
    int i1 = (node + 1 < N) ? rowptr[node + 1] : E;
    float4 acc = {0.f, 0.f, 0.f, 0.f};
    int i = i0 + g2;
    int iB = i + 2;
    int sA = (i < i1) ? csr_src[i] : 0;
    int sB = (iB < i1) ? csr_src[iB] : 0;
    uint2 pA = make_uint2(0u, 0u);
    float wA = 0.f;
    if (i < i1) {
        pA = Hh2[(long long)sA * 4 + c];
        wA = dis[sA] * dd;
    }
    while (i < i1) {
        const int iC = i + 4;
        int sC = (iC < i1) ? csr_src[iC] : 0;
        uint2 pB = Hh2[(long long)sB * 4 + c];
        float wB = (iB < i1) ? dis[sB] * dd : 0.f;
        float4 v = h4_to_f4(pA);
        acc.x += v.x * wA; acc.y += v.y * wA;
        acc.z += v.z * wA; acc.w += v.w * wA;
        i = iB; iB = iC; sA = sB; sB = sC; pA = pB; wA = wB;
    }
    acc.x += __shfl_xor(acc.x, 4);
    acc.y += __shfl_xor(acc.y, 4);
    acc.z += __shfl_xor(acc.z, 4);
    acc.w += __shfl_xor(acc.w, 4);
    if (g2 == 0) {
        float4 h = h4_to_f4(Hh2[(long long)node * 4 + c]);
        float sl = dd * dd;
        float4 bb = b4[c];
        acc.x += h.x * sl + bb.x; acc.y += h.y * sl + bb.y;
        acc.z += h.z * sl + bb.z; acc.w += h.w * sl + bb.w;
        out4[(long long)node * 4 + c] = acc;
    }
}

// ---------------- pooling ----------------
__global__ __launch_bounds__(256) void pool_kernel(const float4* __restrict__ H4,
                                                   const int* __restrict__ batch,
                                                   float* __restrict__ sums,
                                                   float* __restrict__ cnts, int N) {
    __shared__ float sBin[16][16];
    __shared__ float sCnt[16];
    const int t = threadIdx.x;
    sBin[t >> 4][t & 15] = 0.f;
    if (t < 16) sCnt[t] = 0.f;
    __syncthreads();
    const int n0 = blockIdx.x * 256;
    const int g0 = batch[n0];
    const int nl = t >> 2;
    const int f4 = t & 3;
    float4 acc = {0.f, 0.f, 0.f, 0.f};
    float cnt = 0.f;
    int curli = -1;
    for (int j = 0; j < 4; ++j) {
        int node = n0 + nl * 4 + j;
        if (node >= N) break;
        int li = batch[node] - g0;
        if (li != curli) {
            if (curli >= 0) {
                if (curli < 16) {
                    float* bp = &sBin[curli][f4 * 4];
                    atomicAdd(bp + 0, acc.x); atomicAdd(bp + 1, acc.y);
                    atomicAdd(bp + 2, acc.z); atomicAdd(bp + 3, acc.w);
                    if (f4 == 0) atomicAdd(&sCnt[curli], cnt);
                } else {
                    float* gp = &sums[(g0 + curli) * OUTF + f4 * 4];
                    atomicAdd(gp + 0, acc.x); atomicAdd(gp + 1, acc.y);
                    atomicAdd(gp + 2, acc.z); atomicAdd(gp + 3, acc.w);
                    if (f4 == 0) atomicAdd(&cnts[g0 + curli], cnt);
                }
            }
            acc.x = acc.y = acc.z = acc.w = 0.f; cnt = 0.f; curli = li;
        }
        float4 v = H4[(long long)node * 4 + f4];
        acc.x += v.x; acc.y += v.y; acc.z += v.z; acc.w += v.w;
        cnt += 1.f;
    }
    if (curli >= 0) {
        if (curli < 16) {
            float* bp = &sBin[curli][f4 * 4];
            atomicAdd(bp + 0, acc.x); atomicAdd(bp + 1, acc.y);
            atomicAdd(bp + 2, acc.z); atomicAdd(bp + 3, acc.w);
            if (f4 == 0) atomicAdd(&sCnt[curli], cnt);
        } else {
            float* gp = &sums[(g0 + curli) * OUTF + f4 * 4];
            atomicAdd(gp + 0, acc.x); atomicAdd(gp + 1, acc.y);
            atomicAdd(gp + 2, acc.z); atomicAdd(gp + 3, acc.w);
            if (f4 == 0) atomicAdd(&cnts[g0 + curli], cnt);
        }
    }
    __syncthreads();
    int bg = t >> 4, bf = t & 15;
    int g = g0 + bg;
    if (g < NGRAPH) {
        float v = sBin[bg][bf];
        if (v != 0.f) atomicAdd(&sums[g * OUTF + bf], v);
        if (bf == 0) {
            float c = sCnt[bg];
            if (c != 0.f) atomicAdd(&cnts[g], c);
        }
    }
}

__global__ void divide_kernel(const float* __restrict__ sums, const float* __restrict__ counts,
                              float* __restrict__ out) {
    int i = blockIdx.x * blockDim.x + threadIdx.x;
    if (i < NGRAPH * OUTF) out[i] = sums[i] / fmaxf(counts[i >> 4], 1.0f);
}

extern "C" void kernel_launch(void* const* d_in, const int* in_sizes, int n_in,
                              void* d_out, int out_size, void* d_ws, size_t ws_size,
                              hipStream_t stream) {
    const float* x     = (const float*)d_in[0];
    const int*   ei    = (const int*)d_in[1];
    const int*   batch = (const int*)d_in[2];
    const float* W1 = (const float*)d_in[3];
    const float* b1 = (const float*)d_in[4];
    const float* W2 = (const float*)d_in[5];
    const float* b2 = (const float*)d_in[6];
    const float* W3 = (const float*)d_in[7];
    const float* b3 = (const float*)d_in[8];
    float* out = (float*)d_out;

    const int N = in_sizes[2];          // 100000
    const int E = in_sizes[1] / 2;      // 1200000
    const int* src = ei;
    const int* dst = ei + E;

    const int nchunks = (E + CE - 1) / CE;        // 586
    const int NGB = NG * NRNG;                    // 512 counting-sort blocks

    // workspace layout (4-byte units)
    float*    ws      = (float*)d_ws;
    float*    dis     = ws;                          // N floats
    float*    bufA    = dis + N;                     // 25.6 MB: cntmat -> T1/T2/T3 fp16 tables
    float*    bufB    = bufA + (size_t)N * HID;      // 25.6 MB: seg -> A1/A2 fp16 -> f32 pool in
    float*    sums    = bufB + (size_t)N * HID;      // 500*16
    float*    cnts    = sums + NGRAPH * OUTF;        // 500
    int*      rowptr  = (int*)(cnts + NGRAPH);       // N ints
    int*      csr_src = rowptr + N;                  // E ints
    int*      segcnt  = csr_src + E;                 // nseg ints
    int*      aux     = segcnt + nchunks * NRNG;     // <=128 ints
    uint2*    seg     = (uint2*)bufB;                // nseg*CAP uint2 = 19.2 MB < 25.6 MB
    int*      cntmat  = (int*)bufA;                  // NG*N ints = 12.8 MB < 25.6 MB
    __half*   HhA     = (__half*)bufA;               // fp16 tables (after cntmat dead)
    __half*   HhB     = (__half*)bufB;               // fp16 agg out (after seg dead)

    const int B = 256;
    const int nb = (N + 1023) / 1024;
    const int rangeSize = (N + NRNG - 1) / NRNG;

    // ---- CSR build: atomic-free counting sort (LDS atomics only)
    part_kernel<<<nchunks, B, 0, stream>>>(src, dst, seg, segcnt, E, rangeSize);
    count_kernel<<<NGB, B, 0, stream>>>(seg, segcnt, cntmat, N, rangeSize, nchunks);
    scan1_kernel<<<nb, 1024, 0, stream>>>(cntmat, rowptr, aux, dis, sums, N);
    scan3_kernel<<<nb, 1024, 0, stream>>>(rowptr, aux, N, nb);
    scatter_kernel<<<NGB, B, 0, stream>>>(seg, segcnt, cntmat, rowptr, csr_src, N, rangeSize, nchunks);

    const int gb = (N + 63) / 64;

    // ---- layer 1: x @ W1 -> T1 (bufA, fp16) ----
    mfma_gemm_kernel<IN_DIM, HID, false><<<gb, B, 0, stream>>>(x, W1, HhA, N);
    agg64_kernel<<<(N + 15) / 16, B, 0, stream>>>(HhA, rowptr, csr_src,
                                                  dis, (const float4*)b1, (uint4*)HhB, N, E);

    // ---- layer 2: A1 @ W2 -> T2 (bufA, fp16) ----
    mfma_gemm_kernel<HID, HID, true><<<gb, B, 0, stream>>>(HhB, W2, HhA, N);
    agg64_kernel<<<(N + 15) / 16, B, 0, stream>>>(HhA, rowptr, csr_src,
                                                  dis, (const float4*)b2, (uint4*)HhB, N, E);

    // ---- layer 3: A2 @ W3 -> T3 (bufA, fp16) ----
    mfma_gemm_kernel<HID, OUTF, true><<<gb, B, 0, stream>>>(HhB, W3, HhA, N);
    //      agg16(T3) -> pool input (bufB, f32; seg dead)
    agg16_kernel<<<(N + 31) / 32, B, 0, stream>>>(HhA, rowptr, csr_src,
                                                  dis, (const float4*)b3, (float4*)bufB, N, E);

    // ---- global mean pool ----
    pool_kernel<<<(N + 255) / 256, B, 0, stream>>>((const float4*)bufB, batch, sums, cnts, N);
    divide_kernel<<<(NGRAPH * OUTF + B - 1) / B, B, 0, stream>>>(sums, cnts, out);
}